// Round 1
// 488.852 us; speedup vs baseline: 1.5697x; 1.5697x over previous
//
#include <hip/hip_runtime.h>

// FlashMultiHeadAttention  B=4 S=2048 HIDDEN=1024 H=16 Dh=64 (fp32 I/O)
// r6: qkv/out projections rewritten as LDS-staged bf16 GEMMs (m97 structure:
//     128x128 tile, BK=32, global_load_lds width=16, 2 barriers/K-step).
//     Inputs pre-converted to bf16 once (memory-bound) so the GEMM inner loop
//     is pure ds_read_b128 + MFMA — old version was latency-bound at 132 TF
//     (MfmaUtil 5.4%) doing per-lane fp32 loads + f2b in the K-loop.
// ws (u16 elems, 96 MB): Qw[0,8M) Kw[8M,16M) Vt[16M,24M) Ow[24M,32M) rel'[32M,48M)
//     aliases: Xq_bf16 = Ow region (attn writes Ow after qkv done)
//              Xk/Xv_bf16 = rel' region (rel_cvt runs after qkv_proj)
//              Wq/Wk/Wv_bf16 = d_out scratch (overwritten by out_proj at the end)
//              Wo_bf16 = Qw region (dead after attn)

#define SEQ 2048
#define NH 16
#define DH 64
#define HID 1024
#define QSCALE 0.18033688011112f   // 0.125 * log2(e)

typedef short bf16x8 __attribute__((ext_vector_type(8)));
typedef float f32x4  __attribute__((ext_vector_type(4)));
typedef unsigned short u16;
typedef unsigned short u16x4 __attribute__((ext_vector_type(4)));
typedef unsigned short u16x8 __attribute__((ext_vector_type(8)));

__device__ __forceinline__ float b2f(u16 u) {
    union { unsigned i; float f; } x; x.i = ((unsigned)u) << 16; return x.f;
}
__device__ __forceinline__ u16 f2b(float f) {
    union { float f; unsigned i; } x; x.f = f;
    unsigned r = x.i + 0x7fffu + ((x.i >> 16) & 1u);
    return (u16)(r >> 16);
}

typedef const __attribute__((address_space(1))) unsigned int guint;
typedef __attribute__((address_space(3))) unsigned int luint;
__device__ __forceinline__ void gload_lds16(const u16* g, u16* l) {
    __builtin_amdgcn_global_load_lds((guint*)g, (luint*)l, 16, 0, 0);
}

// ---------------- fp32 -> bf16 bulk convert (vectorized, grid-stride) ----------------
__global__ __launch_bounds__(256) void cvt_bf16_kernel(
    const float* __restrict__ in, u16* __restrict__ out, int n8)
{
    int i = blockIdx.x * 256 + threadIdx.x;
    const int stride = gridDim.x * 256;
    for (; i < n8; i += stride) {
        f32x4 a = *(const f32x4*)(in + (size_t)i * 8);
        f32x4 b = *(const f32x4*)(in + (size_t)i * 8 + 4);
        u16x8 o;
#pragma unroll
        for (int j = 0; j < 4; ++j) { o[j] = f2b(a[j]); o[j + 4] = f2b(b[j]); }
        *(u16x8*)(out + (size_t)i * 8) = o;
    }
}

// ---------------- rel -> bf16, pre-scaled into exp2 domain ----------------
__global__ __launch_bounds__(256) void rel_cvt_kernel(
    const float* __restrict__ rel, u16* __restrict__ out)
{
    const size_t i0 = ((size_t)blockIdx.x * 256 + threadIdx.x) * 4;
#pragma unroll
    for (int it = 0; it < 16; ++it) {
        const size_t i = i0 + (size_t)it * 1048576;
        f32x4 x = *(const f32x4*)(rel + i);
        u16x4 o;
#pragma unroll
        for (int j = 0; j < 4; ++j) o[j] = f2b(x[j] * QSCALE);
        *(u16x4*)(out + i) = o;
    }
}

// ---------------- QKV projection: bf16 LDS-staged GEMM, Y = X @ W^T + b ----------------
// 128x128 tile, BK=32, 4 waves (2x2), global_load_lds width=16 into linear LDS.
__global__ __launch_bounds__(256) void qkv_proj_kernel(
    const u16* __restrict__ xq, const u16* __restrict__ xk, const u16* __restrict__ xv,
    const u16* __restrict__ wq, const u16* __restrict__ wk, const u16* __restrict__ wv,
    const float* __restrict__ bq, const float* __restrict__ bk, const float* __restrict__ bv,
    u16* __restrict__ Qw, u16* __restrict__ Kw, u16* __restrict__ Vw)
{
    __shared__ __align__(16) u16 As[128 * 32];
    __shared__ __align__(16) u16 Bs[128 * 32];

    const int tid  = threadIdx.x;
    const int w    = tid >> 6;
    const int lane = tid & 63;
    const int l16  = lane & 15;
    const int quad = lane >> 4;

    const int bid = blockIdx.x;
    const int sel = bid >> 9;            // 0=q 1=k 2=v  (512 blocks each)
    const int rem = bid & 511;
    const int tm = rem >> 3, tn = rem & 7;
    const int m0 = tm << 7, n0 = tn << 7;

    const u16* X    = sel == 0 ? xq : (sel == 1 ? xk : xv);
    const u16* W    = sel == 0 ? wq : (sel == 1 ? wk : wv);
    const float* bias = sel == 0 ? bq : (sel == 1 ? bk : bv);

    // staging: 8 chunks of 1KB per tile; wave w stages chunks {w, w+4}
    const int crow = lane >> 2;          // row within chunk 0..15
    const int cofs = (lane & 3) << 3;    // elem offset 0,8,16,24

    f32x4 acc[4][4];
    const f32x4 zero = {0.f, 0.f, 0.f, 0.f};
#pragma unroll
    for (int r = 0; r < 4; ++r)
#pragma unroll
        for (int c = 0; c < 4; ++c) acc[r][c] = zero;

    const int wr = (w >> 1) << 6;        // wave sub-tile origin (64x64)
    const int wc = (w & 1) << 6;

    for (int k0 = 0; k0 < 1024; k0 += 32) {
#pragma unroll
        for (int c = 0; c < 2; ++c) {
            const int ch  = w + c * 4;
            const int row = ch * 16 + crow;
            gload_lds16(X + (size_t)(m0 + row) * 1024 + k0 + cofs, As + ch * 512 + lane * 8);
            gload_lds16(W + (size_t)(n0 + row) * 1024 + k0 + cofs, Bs + ch * 512 + lane * 8);
        }
        __syncthreads();
        bf16x8 a[4], b[4];
#pragma unroll
        for (int r = 0; r < 4; ++r) a[r] = *(const bf16x8*)(As + (wr + r * 16 + l16) * 32 + quad * 8);
#pragma unroll
        for (int c = 0; c < 4; ++c) b[c] = *(const bf16x8*)(Bs + (wc + c * 16 + l16) * 32 + quad * 8);
#pragma unroll
        for (int r = 0; r < 4; ++r)
#pragma unroll
            for (int c = 0; c < 4; ++c)
                acc[r][c] = __builtin_amdgcn_mfma_f32_16x16x32_bf16(a[r], b[c], acc[r][c], 0, 0, 0);
        __syncthreads();
    }

    // C layout: col(n)=lane&15, row(m)=quad*4+reg
#pragma unroll
    for (int c = 0; c < 4; ++c) {
        const int n = n0 + wc + c * 16 + l16;
        const float bn = bias[n];
        const int h = n >> 6, d = n & 63;
#pragma unroll
        for (int r = 0; r < 4; ++r) {
#pragma unroll
            for (int g = 0; g < 4; ++g) {
                const int m  = m0 + wr + r * 16 + quad * 4 + g;
                const int b_ = m >> 11, s_ = m & 2047;
                const float val = acc[r][c][g] + bn;
                if (sel == 0)
                    Qw[(((size_t)(b_ * 16 + h)) * 2048 + s_) * 64 + d] = f2b(val * QSCALE);
                else if (sel == 1)
                    Kw[(((size_t)(b_ * 16 + h)) * 2048 + s_) * 64 + d] = f2b(val);
                else
                    Vw[(((size_t)(b_ * 16 + h)) * 64 + d) * 2048 + s_] = f2b(val);  // transposed
            }
        }
    }
}

// ---------------- Flash attention: 4 waves/block, 32 q per wave (unchanged) ----------------
__global__ __launch_bounds__(256, 2) void attn_kernel(
    const u16* __restrict__ Qb, const u16* __restrict__ Kb,
    const u16* __restrict__ Vb, const u16* __restrict__ relb,
    u16* __restrict__ Ob)
{
    __shared__ __align__(16) u16 lds[18432];   // Ks 64x72 | Vt 64x72 | Pl 4x(32x72) = 36864 B
    u16* Ks = lds;
    u16* Vt = lds + 4608;

    const int tid  = threadIdx.x;
    const int w    = tid >> 6;
    const int lane = tid & 63;
    const int l16  = lane & 15;
    const int quad = lane >> 4;
    u16* Pl = lds + 9216 + w * 2304;

    const int bh = blockIdx.x & 63;
    const int i  = blockIdx.x >> 6;              // 16 strips of 128 queries
    const int qb = (i < 8) ? i : (23 - i);       // pair strip j with 15-j for balance
    const int b  = bh >> 4, h = bh & 15;
    const int q0w = qb * 128 + w * 32;           // wave's 32-query window

    // Q A-fragments (persistent; Q pre-scaled by QSCALE)
    bf16x8 qa[2][2];
    const u16* Qp = Qb + (size_t)bh * SEQ * DH;
#pragma unroll
    for (int mt = 0; mt < 2; ++mt)
#pragma unroll
        for (int ks = 0; ks < 2; ++ks)
            qa[mt][ks] = *(const bf16x8*)(Qp + (size_t)(q0w + mt * 16 + l16) * 64 + ks * 32 + quad * 8);

    f32x4 o[2][4], mrow[2], lrow[2];
    const f32x4 zero = {0.f, 0.f, 0.f, 0.f};
    const f32x4 ninf = {-1e30f, -1e30f, -1e30f, -1e30f};
#pragma unroll
    for (int mt = 0; mt < 2; ++mt) {
        mrow[mt] = ninf; lrow[mt] = zero;
#pragma unroll
        for (int dt = 0; dt < 4; ++dt) o[mt][dt] = zero;
    }

    const u16* relB = relb + (size_t)b * SEQ * SEQ;
    const u16* Kg = Kb + (size_t)bh * SEQ * DH;
    const u16* Vg = Vb + (size_t)bh * DH * SEQ;

    const int ntiles  = qb * 2 + 2;              // staged by the block
    const int mytiles = qb * 2 + (w >> 1) + 1;   // processed by this wave

    // staging indices: 512 16B-chunks per tile pair-kind, 2 per thread
    const int c0 = tid, c1 = tid + 256;
    const int r0 = c0 >> 3, o0 = (c0 & 7) << 3;
    const int r1 = c1 >> 3, o1 = (c1 & 7) << 3;

    // prefetch tile 0
    bf16x8 kreg0 = *(const bf16x8*)(Kg + (size_t)r0 * 64 + o0);
    bf16x8 kreg1 = *(const bf16x8*)(Kg + (size_t)r1 * 64 + o1);
    bf16x8 vreg0 = *(const bf16x8*)(Vg + (size_t)r0 * 2048 + o0);
    bf16x8 vreg1 = *(const bf16x8*)(Vg + (size_t)r1 * 2048 + o1);

    for (int kt = 0; kt < ntiles; ++kt) {
        const int k0 = kt << 6;
        // regs -> LDS, then issue next tile's loads (latency hidden under compute)
        *(bf16x8*)(Ks + r0 * 72 + o0) = kreg0;
        *(bf16x8*)(Ks + r1 * 72 + o1) = kreg1;
        *(bf16x8*)(Vt + r0 * 72 + o0) = vreg0;
        *(bf16x8*)(Vt + r1 * 72 + o1) = vreg1;
        const int kn = (kt + 1 < ntiles ? kt + 1 : kt) << 6;
        kreg0 = *(const bf16x8*)(Kg + (size_t)(kn + r0) * 64 + o0);
        kreg1 = *(const bf16x8*)(Kg + (size_t)(kn + r1) * 64 + o1);
        vreg0 = *(const bf16x8*)(Vg + (size_t)r0 * 2048 + kn + o0);
        vreg1 = *(const bf16x8*)(Vg + (size_t)r1 * 2048 + kn + o1);
        __syncthreads();

        if (kt < mytiles) {
            // ---- scores: C init = rel' (bf16 pre-scaled), MFMA adds scaled QK^T ----
            f32x4 s[2][4];
#pragma unroll
            for (int mt = 0; mt < 2; ++mt)
#pragma unroll
                for (int nt = 0; nt < 4; ++nt)
#pragma unroll
                    for (int g = 0; g < 4; ++g)
                        s[mt][nt][g] = b2f(relB[(size_t)(q0w + mt * 16 + quad * 4 + g) * SEQ
                                                + k0 + nt * 16 + l16]);
#pragma unroll
            for (int nt = 0; nt < 4; ++nt) {
                bf16x8 kb0 = *(const bf16x8*)(Ks + (nt * 16 + l16) * 72 + quad * 8);
                bf16x8 kb1 = *(const bf16x8*)(Ks + (nt * 16 + l16) * 72 + 32 + quad * 8);
#pragma unroll
                for (int mt = 0; mt < 2; ++mt) {
                    s[mt][nt] = __builtin_amdgcn_mfma_f32_16x16x32_bf16(qa[mt][0], kb0, s[mt][nt], 0, 0, 0);
                    s[mt][nt] = __builtin_amdgcn_mfma_f32_16x16x32_bf16(qa[mt][1], kb1, s[mt][nt], 0, 0, 0);
                }
            }
            // ---- causal mask (diagonal tile only) ----
            if (kt == mytiles - 1) {
#pragma unroll
                for (int mt = 0; mt < 2; ++mt)
#pragma unroll
                    for (int nt = 0; nt < 4; ++nt)
#pragma unroll
                        for (int g = 0; g < 4; ++g) {
                            const int q = q0w + mt * 16 + quad * 4 + g;
                            const int k = k0 + nt * 16 + l16;
                            if (k > q) s[mt][nt][g] = -1e30f;
                        }
            }
            // ---- online softmax (exp2 domain) ----
#pragma unroll
            for (int mt = 0; mt < 2; ++mt) {
                f32x4 t;
#pragma unroll
                for (int g = 0; g < 4; ++g)
                    t[g] = fmaxf(fmaxf(s[mt][0][g], s[mt][1][g]), fmaxf(s[mt][2][g], s[mt][3][g]));
#pragma unroll
                for (int off = 1; off < 16; off <<= 1)
#pragma unroll
                    for (int g = 0; g < 4; ++g)
                        t[g] = fmaxf(t[g], __shfl_xor(t[g], off, 64));
                f32x4 mn, alpha;
#pragma unroll
                for (int g = 0; g < 4; ++g) {
                    mn[g] = fmaxf(mrow[mt][g], t[g]);
                    alpha[g] = __builtin_amdgcn_exp2f(mrow[mt][g] - mn[g]);
                }
                mrow[mt] = mn;
#pragma unroll
                for (int g = 0; g < 4; ++g) lrow[mt][g] *= alpha[g];
#pragma unroll
                for (int dt = 0; dt < 4; ++dt)
#pragma unroll
                    for (int g = 0; g < 4; ++g) o[mt][dt][g] *= alpha[g];
#pragma unroll
                for (int nt = 0; nt < 4; ++nt)
#pragma unroll
                    for (int g = 0; g < 4; ++g)
                        s[mt][nt][g] = __builtin_amdgcn_exp2f(s[mt][nt][g] - mn[g]);
                f32x4 rs;
#pragma unroll
                for (int g = 0; g < 4; ++g)
                    rs[g] = (s[mt][0][g] + s[mt][1][g]) + (s[mt][2][g] + s[mt][3][g]);
#pragma unroll
                for (int off = 1; off < 16; off <<= 1)
#pragma unroll
                    for (int g = 0; g < 4; ++g)
                        rs[g] += __shfl_xor(rs[g], off, 64);
#pragma unroll
                for (int g = 0; g < 4; ++g) lrow[mt][g] += rs[g];
            }
            // ---- P -> bf16 -> per-wave LDS ----
#pragma unroll
            for (int mt = 0; mt < 2; ++mt)
#pragma unroll
                for (int nt = 0; nt < 4; ++nt)
#pragma unroll
                    for (int g = 0; g < 4; ++g)
                        Pl[(mt * 16 + quad * 4 + g) * 72 + nt * 16 + l16] = f2b(s[mt][nt][g]);
            // ---- PV ----
            bf16x8 pa[2][2];
#pragma unroll
            for (int mt = 0; mt < 2; ++mt)
#pragma unroll
                for (int ks = 0; ks < 2; ++ks)
                    pa[mt][ks] = *(const bf16x8*)(Pl + (mt * 16 + l16) * 72 + ks * 32 + quad * 8);
#pragma unroll
            for (int dt = 0; dt < 4; ++dt) {
                bf16x8 vb0 = *(const bf16x8*)(Vt + (dt * 16 + l16) * 72 + quad * 8);
                bf16x8 vb1 = *(const bf16x8*)(Vt + (dt * 16 + l16) * 72 + 32 + quad * 8);
#pragma unroll
                for (int mt = 0; mt < 2; ++mt) {
                    o[mt][dt] = __builtin_amdgcn_mfma_f32_16x16x32_bf16(pa[mt][0], vb0, o[mt][dt], 0, 0, 0);
                    o[mt][dt] = __builtin_amdgcn_mfma_f32_16x16x32_bf16(pa[mt][1], vb1, o[mt][dt], 0, 0, 0);
                }
            }
        }
        __syncthreads();
    }

    // ---- epilogue: O/l -> per-wave LDS -> coalesced stores ----
#pragma unroll
    for (int mt = 0; mt < 2; ++mt) {
        f32x4 linv;
#pragma unroll
        for (int g = 0; g < 4; ++g) linv[g] = 1.0f / lrow[mt][g];
#pragma unroll
        for (int dt = 0; dt < 4; ++dt)
#pragma unroll
            for (int g = 0; g < 4; ++g)
                Pl[(mt * 16 + quad * 4 + g) * 72 + dt * 16 + l16] = f2b(o[mt][dt][g] * linv[g]);
    }
#pragma unroll
    for (int p = 0; p < 4; ++p) {
        const int c = lane + p * 64;
        const int row = c >> 3, col = (c & 7) << 3;
        bf16x8 t = *(const bf16x8*)(Pl + row * 72 + col);
        *(bf16x8*)(Ob + ((size_t)b * SEQ + q0w + row) * HID + h * DH + col) = t;
    }
}

// ---------------- Output projection: bf16 LDS-staged GEMM, out = O @ Wout^T + bout ----------------
__global__ __launch_bounds__(256) void out_proj_kernel(
    const u16* __restrict__ X, const u16* __restrict__ W,
    const float* __restrict__ bias, float* __restrict__ out)
{
    __shared__ __align__(16) u16 As[128 * 32];
    __shared__ __align__(16) u16 Bs[128 * 32];

    const int tid  = threadIdx.x;
    const int w    = tid >> 6;
    const int lane = tid & 63;
    const int l16  = lane & 15;
    const int quad = lane >> 4;

    const int bid = blockIdx.x;
    const int tm = bid >> 3, tn = bid & 7;
    const int m0 = tm << 7, n0 = tn << 7;

    const int crow = lane >> 2;
    const int cofs = (lane & 3) << 3;

    f32x4 acc[4][4];
    const f32x4 zero = {0.f, 0.f, 0.f, 0.f};
#pragma unroll
    for (int r = 0; r < 4; ++r)
#pragma unroll
        for (int c = 0; c < 4; ++c) acc[r][c] = zero;

    const int wr = (w >> 1) << 6;
    const int wc = (w & 1) << 6;

    for (int k0 = 0; k0 < 1024; k0 += 32) {
#pragma unroll
        for (int c = 0; c < 2; ++c) {
            const int ch  = w + c * 4;
            const int row = ch * 16 + crow;
            gload_lds16(X + (size_t)(m0 + row) * 1024 + k0 + cofs, As + ch * 512 + lane * 8);
            gload_lds16(W + (size_t)(n0 + row) * 1024 + k0 + cofs, Bs + ch * 512 + lane * 8);
        }
        __syncthreads();
        bf16x8 a[4], b[4];
#pragma unroll
        for (int r = 0; r < 4; ++r) a[r] = *(const bf16x8*)(As + (wr + r * 16 + l16) * 32 + quad * 8);
#pragma unroll
        for (int c = 0; c < 4; ++c) b[c] = *(const bf16x8*)(Bs + (wc + c * 16 + l16) * 32 + quad * 8);
#pragma unroll
        for (int r = 0; r < 4; ++r)
#pragma unroll
            for (int c = 0; c < 4; ++c)
                acc[r][c] = __builtin_amdgcn_mfma_f32_16x16x32_bf16(a[r], b[c], acc[r][c], 0, 0, 0);
        __syncthreads();
    }

#pragma unroll
    for (int c = 0; c < 4; ++c) {
        const int n = n0 + wc + c * 16 + l16;
        const float bn = bias[n];
#pragma unroll
        for (int r = 0; r < 4; ++r) {
#pragma unroll
            for (int g = 0; g < 4; ++g) {
                const int m = m0 + wr + r * 16 + quad * 4 + g;
                out[(size_t)m * 1024 + n] = acc[r][c][g] + bn;
            }
        }
    }
}

extern "C" void kernel_launch(void* const* d_in, const int* in_sizes, int n_in,
                              void* d_out, int out_size, void* d_ws, size_t ws_size,
                              hipStream_t stream)
{
    const float* q   = (const float*)d_in[0];
    const float* k   = (const float*)d_in[1];
    const float* v   = (const float*)d_in[2];
    const float* rel = (const float*)d_in[3];
    // d_in[4] = attn_mask: statically causal tril, not read
    const float* wq = (const float*)d_in[5];  const float* bq = (const float*)d_in[6];
    const float* wk = (const float*)d_in[7];  const float* bk = (const float*)d_in[8];
    const float* wv = (const float*)d_in[9];  const float* bv = (const float*)d_in[10];
    const float* wo = (const float*)d_in[11]; const float* bo = (const float*)d_in[12];

    u16* ws = (u16*)d_ws;                 // 96 MB used
    u16* Qw   = ws;
    u16* Kw   = ws + 8388608ULL;
    u16* Vw   = ws + 16777216ULL;
    u16* Ow   = ws + 25165824ULL;
    u16* relb = ws + 33554432ULL;

    // bf16 staging aliases (dead by the time their hosts are written):
    u16* Xqb = Ow;                         // [24M,32M): overwritten by attn (after qkv)
    u16* Xkb = relb;                       // [32M,40M): overwritten by rel_cvt (after qkv)
    u16* Xvb = relb + 8388608ULL;          // [40M,48M)
    u16* Wqb = (u16*)d_out;                // d_out as scratch; out_proj rewrites it at the end
    u16* Wkb = Wqb + 1048576ULL;
    u16* Wvb = Wqb + 2097152ULL;
    u16* Wob = Qw;                         // Qw dead after attn

    // X, W -> bf16
    cvt_bf16_kernel<<<1024, 256, 0, stream>>>(q, Xqb, 1048576);
    cvt_bf16_kernel<<<1024, 256, 0, stream>>>(k, Xkb, 1048576);
    cvt_bf16_kernel<<<1024, 256, 0, stream>>>(v, Xvb, 1048576);
    cvt_bf16_kernel<<<512, 256, 0, stream>>>(wq, Wqb, 131072);
    cvt_bf16_kernel<<<512, 256, 0, stream>>>(wk, Wkb, 131072);
    cvt_bf16_kernel<<<512, 256, 0, stream>>>(wv, Wvb, 131072);

    qkv_proj_kernel<<<1536, 256, 0, stream>>>(Xqb, Xkb, Xvb, Wqb, Wkb, Wvb,
                                              bq, bk, bv, Qw, Kw, Vw);
    rel_cvt_kernel<<<1024, 256, 0, stream>>>(rel, relb);     // overwrites Xkb/Xvb (dead)
    attn_kernel<<<1024, 256, 0, stream>>>(Qw, Kw, Vw, relb, Ow);  // overwrites Xqb (dead)
    cvt_bf16_kernel<<<512, 256, 0, stream>>>(wo, Wob, 131072);    // into dead Qw region
    out_proj_kernel<<<512, 256, 0, stream>>>(Ow, Wob, bo, (float*)d_out);
}

// Round 2
// 482.518 us; speedup vs baseline: 1.5903x; 1.0131x over previous
//
#include <hip/hip_runtime.h>

// FlashMultiHeadAttention  B=4 S=2048 HIDDEN=1024 H=16 Dh=64 (fp32 I/O)
// r7: attn latency fixes.
//  (a) rel pre-permuted into MFMA C-fragment order by rel_perm_kernel:
//      rel_perm[b][qt16][kt64][lane][nt][g] (u16). attn s-init becomes
//      4x16B coalesced vector loads per tile, prefetched one tile ahead
//      (was: 32 scalar u16 global loads per tile per lane = latency-bound,
//      MfmaUtil 10.7 / VALUBusy 39 / occ 20.5).
//  (b) uniform blocks: strip p paired with strip 15-p sequentially ->
//      512 blocks x 34 tile-units each; no per-CU tail imbalance.
// ws (u16 elems, 96 MB): Qw[0,8M) Kw[8M,16M) Vt[16M,24M) Ow[24M,32M) rel'[32M,48M)
//     aliases: Xq_bf16 = Ow region, Xk/Xv_bf16 = rel' region (rel_perm runs after
//     qkv), Wq/Wk/Wv_bf16 = d_out scratch, Wo_bf16 = Qw region (dead after attn).

#define SEQ 2048
#define NH 16
#define DH 64
#define HID 1024
#define QSCALE 0.18033688011112f   // 0.125 * log2(e)

typedef short bf16x8 __attribute__((ext_vector_type(8)));
typedef float f32x4  __attribute__((ext_vector_type(4)));
typedef unsigned short u16;
typedef unsigned short u16x4 __attribute__((ext_vector_type(4)));
typedef unsigned short u16x8 __attribute__((ext_vector_type(8)));

__device__ __forceinline__ float b2f(u16 u) {
    union { unsigned i; float f; } x; x.i = ((unsigned)u) << 16; return x.f;
}
__device__ __forceinline__ u16 f2b(float f) {
    union { float f; unsigned i; } x; x.f = f;
    unsigned r = x.i + 0x7fffu + ((x.i >> 16) & 1u);
    return (u16)(r >> 16);
}

typedef const __attribute__((address_space(1))) unsigned int guint;
typedef __attribute__((address_space(3))) unsigned int luint;
__device__ __forceinline__ void gload_lds16(const u16* g, u16* l) {
    __builtin_amdgcn_global_load_lds((guint*)g, (luint*)l, 16, 0, 0);
}

// ---------------- fp32 -> bf16 bulk convert (vectorized, grid-stride) ----------------
__global__ __launch_bounds__(256) void cvt_bf16_kernel(
    const float* __restrict__ in, u16* __restrict__ out, int n8)
{
    int i = blockIdx.x * 256 + threadIdx.x;
    const int stride = gridDim.x * 256;
    for (; i < n8; i += stride) {
        f32x4 a = *(const f32x4*)(in + (size_t)i * 8);
        f32x4 b = *(const f32x4*)(in + (size_t)i * 8 + 4);
        u16x8 o;
#pragma unroll
        for (int j = 0; j < 4; ++j) { o[j] = f2b(a[j]); o[j + 4] = f2b(b[j]); }
        *(u16x8*)(out + (size_t)i * 8) = o;
    }
}

// ---------------- rel -> bf16, pre-scaled, permuted to MFMA C-fragment order ----------
// out[b][qt16 (128)][kt64 (32)][lane (64)][nt (4)][g (4)]  where for element (q,k):
//   qt16=q>>4, kt64=k>>6, lane=((q>>2)&3)*16 + (k&15), nt=(k>>4)&3, g=q&3
__global__ __launch_bounds__(256) void rel_perm_kernel(
    const float* __restrict__ rel, u16* __restrict__ out)
{
    __shared__ u16 pl[4096];             // 4 qt16-subtiles x 1024
    const int t   = threadIdx.x;
    const int blk = blockIdx.x;          // 4096 = 4b x 32qc x 32kc
    const int b   = blk >> 10;
    const int qc  = (blk >> 5) & 31;
    const int kc  = blk & 31;
    const int qloc  = t >> 2;            // 0..63
    const int kloc0 = (t & 3) << 4;      // 0,16,32,48

    const float* src = rel + ((size_t)b * SEQ + qc * 64 + qloc) * SEQ + kc * 64 + kloc0;
    const int qt   = qloc >> 4;
    const int quad = (qloc >> 2) & 3;
    const int g    = qloc & 3;
    const int nt   = t & 3;
    u16* dst = pl + qt * 1024 + quad * 256 + nt * 4 + g;
#pragma unroll
    for (int c = 0; c < 4; ++c) {
        f32x4 x = *(const f32x4*)(src + c * 4);
#pragma unroll
        for (int j = 0; j < 4; ++j)
            dst[(c * 4 + j) * 16] = f2b(x[j] * QSCALE);
    }
    __syncthreads();
    const size_t obase = (((size_t)b * 128 + qc * 4) * 32 + kc) * 1024;
#pragma unroll
    for (int q2 = 0; q2 < 4; ++q2)
        *(u16x4*)(out + obase + (size_t)q2 * 32768 + t * 4) =
            *(const u16x4*)(pl + q2 * 1024 + t * 4);
}

// ---------------- QKV projection: bf16 LDS-staged GEMM, Y = X @ W^T + b ----------------
__global__ __launch_bounds__(256) void qkv_proj_kernel(
    const u16* __restrict__ xq, const u16* __restrict__ xk, const u16* __restrict__ xv,
    const u16* __restrict__ wq, const u16* __restrict__ wk, const u16* __restrict__ wv,
    const float* __restrict__ bq, const float* __restrict__ bk, const float* __restrict__ bv,
    u16* __restrict__ Qw, u16* __restrict__ Kw, u16* __restrict__ Vw)
{
    __shared__ __align__(16) u16 As[128 * 32];
    __shared__ __align__(16) u16 Bs[128 * 32];

    const int tid  = threadIdx.x;
    const int w    = tid >> 6;
    const int lane = tid & 63;
    const int l16  = lane & 15;
    const int quad = lane >> 4;

    const int bid = blockIdx.x;
    const int sel = bid >> 9;            // 0=q 1=k 2=v  (512 blocks each)
    const int rem = bid & 511;
    const int tm = rem >> 3, tn = rem & 7;
    const int m0 = tm << 7, n0 = tn << 7;

    const u16* X    = sel == 0 ? xq : (sel == 1 ? xk : xv);
    const u16* W    = sel == 0 ? wq : (sel == 1 ? wk : wv);
    const float* bias = sel == 0 ? bq : (sel == 1 ? bk : bv);

    const int crow = lane >> 2;          // row within chunk 0..15
    const int cofs = (lane & 3) << 3;    // elem offset 0,8,16,24

    f32x4 acc[4][4];
    const f32x4 zero = {0.f, 0.f, 0.f, 0.f};
#pragma unroll
    for (int r = 0; r < 4; ++r)
#pragma unroll
        for (int c = 0; c < 4; ++c) acc[r][c] = zero;

    const int wr = (w >> 1) << 6;
    const int wc = (w & 1) << 6;

    for (int k0 = 0; k0 < 1024; k0 += 32) {
#pragma unroll
        for (int c = 0; c < 2; ++c) {
            const int ch  = w + c * 4;
            const int row = ch * 16 + crow;
            gload_lds16(X + (size_t)(m0 + row) * 1024 + k0 + cofs, As + ch * 512 + lane * 8);
            gload_lds16(W + (size_t)(n0 + row) * 1024 + k0 + cofs, Bs + ch * 512 + lane * 8);
        }
        __syncthreads();
        bf16x8 a[4], b[4];
#pragma unroll
        for (int r = 0; r < 4; ++r) a[r] = *(const bf16x8*)(As + (wr + r * 16 + l16) * 32 + quad * 8);
#pragma unroll
        for (int c = 0; c < 4; ++c) b[c] = *(const bf16x8*)(Bs + (wc + c * 16 + l16) * 32 + quad * 8);
#pragma unroll
        for (int r = 0; r < 4; ++r)
#pragma unroll
            for (int c = 0; c < 4; ++c)
                acc[r][c] = __builtin_amdgcn_mfma_f32_16x16x32_bf16(a[r], b[c], acc[r][c], 0, 0, 0);
        __syncthreads();
    }

    // C layout: col(n)=lane&15, row(m)=quad*4+reg
#pragma unroll
    for (int c = 0; c < 4; ++c) {
        const int n = n0 + wc + c * 16 + l16;
        const float bn = bias[n];
        const int h = n >> 6, d = n & 63;
#pragma unroll
        for (int r = 0; r < 4; ++r) {
#pragma unroll
            for (int g = 0; g < 4; ++g) {
                const int m  = m0 + wr + r * 16 + quad * 4 + g;
                const int b_ = m >> 11, s_ = m & 2047;
                const float val = acc[r][c][g] + bn;
                if (sel == 0)
                    Qw[(((size_t)(b_ * 16 + h)) * 2048 + s_) * 64 + d] = f2b(val * QSCALE);
                else if (sel == 1)
                    Kw[(((size_t)(b_ * 16 + h)) * 2048 + s_) * 64 + d] = f2b(val);
                else
                    Vw[(((size_t)(b_ * 16 + h)) * 64 + d) * 2048 + s_] = f2b(val);  // transposed
            }
        }
    }
}

// ---------------- Flash attention: 4 waves/block, 32 q/wave, 2 strips/block ----------------
__global__ __launch_bounds__(256, 2) void attn_kernel(
    const u16* __restrict__ Qb, const u16* __restrict__ Kb,
    const u16* __restrict__ Vb, const u16* __restrict__ relb,
    u16* __restrict__ Ob)
{
    __shared__ __align__(16) u16 lds[18432];   // Ks 64x72 | Vt 64x72 | Pl 4x(32x72)
    u16* Ks = lds;
    u16* Vt = lds + 4608;

    const int tid  = threadIdx.x;
    const int w    = tid >> 6;
    const int lane = tid & 63;
    const int l16  = lane & 15;
    const int quad = lane >> 4;
    u16* Pl = lds + 9216 + w * 2304;

    const int bh = blockIdx.x & 63;
    const int p  = blockIdx.x >> 6;              // 0..7 strip pair
    const int b  = bh >> 4, h = bh & 15;

    const u16* Qp = Qb + (size_t)bh * SEQ * DH;
    const u16* Kg = Kb + (size_t)bh * SEQ * DH;
    const u16* Vg = Vb + (size_t)bh * DH * SEQ;

    // staging indices: 512 16B-chunks per tile pair-kind, 2 per thread
    const int c0 = tid, c1 = tid + 256;
    const int r0 = c0 >> 3, o0 = (c0 & 7) << 3;
    const int r1 = c1 >> 3, o1 = (c1 & 7) << 3;

    for (int sidx = 0; sidx < 2; ++sidx) {
        const int qb  = sidx ? (15 - p) : p;
        const int q0w = qb * 128 + w * 32;       // wave's 32-query window

        // Q A-fragments (persistent; Q pre-scaled by QSCALE)
        bf16x8 qa[2][2];
#pragma unroll
        for (int mt = 0; mt < 2; ++mt)
#pragma unroll
            for (int ks = 0; ks < 2; ++ks)
                qa[mt][ks] = *(const bf16x8*)(Qp + (size_t)(q0w + mt * 16 + l16) * 64 + ks * 32 + quad * 8);

        f32x4 o[2][4], mrow[2], lrow[2];
        const f32x4 zero = {0.f, 0.f, 0.f, 0.f};
        const f32x4 ninf = {-1e30f, -1e30f, -1e30f, -1e30f};
#pragma unroll
        for (int mt = 0; mt < 2; ++mt) {
            mrow[mt] = ninf; lrow[mt] = zero;
#pragma unroll
            for (int dt = 0; dt < 4; ++dt) o[mt][dt] = zero;
        }

        const int ntiles  = qb * 2 + 2;              // staged by the block
        const int mytiles = qb * 2 + (w >> 1) + 1;   // processed by this wave

        // rel (permuted) base for this wave: idx = (b*128+qt)*32768 + kt*1024 + lane*16
        const u16* relW = relb + ((size_t)(b * 128 + (q0w >> 4))) * 32768 + (size_t)lane * 16;

        // prefetch tile 0: K/V chunks + rel fragments
        bf16x8 kreg0 = *(const bf16x8*)(Kg + (size_t)r0 * 64 + o0);
        bf16x8 kreg1 = *(const bf16x8*)(Kg + (size_t)r1 * 64 + o1);
        bf16x8 vreg0 = *(const bf16x8*)(Vg + (size_t)r0 * 2048 + o0);
        bf16x8 vreg1 = *(const bf16x8*)(Vg + (size_t)r1 * 2048 + o1);
        bf16x8 rr[2][2];
        rr[0][0] = *(const bf16x8*)(relW);
        rr[0][1] = *(const bf16x8*)(relW + 8);
        rr[1][0] = *(const bf16x8*)(relW + 32768);
        rr[1][1] = *(const bf16x8*)(relW + 32768 + 8);

        for (int kt = 0; kt < ntiles; ++kt) {
            const int k0 = kt << 6;
            // regs -> LDS
            *(bf16x8*)(Ks + r0 * 72 + o0) = kreg0;
            *(bf16x8*)(Ks + r1 * 72 + o1) = kreg1;
            *(bf16x8*)(Vt + r0 * 72 + o0) = vreg0;
            *(bf16x8*)(Vt + r1 * 72 + o1) = vreg1;

            // s-init from prefetched rel regs (pure VALU, before barrier)
            f32x4 s[2][4];
            if (kt < mytiles) {
#pragma unroll
                for (int mt = 0; mt < 2; ++mt)
#pragma unroll
                    for (int nt = 0; nt < 4; ++nt)
#pragma unroll
                        for (int g = 0; g < 4; ++g)
                            s[mt][nt][g] = b2f((u16)rr[mt][nt >> 1][(nt & 1) * 4 + g]);
            }

            // issue next tile's global loads (latency hidden under compute)
            const int ktn = (kt + 1 < ntiles) ? kt + 1 : kt;
            const int kn  = ktn << 6;
            kreg0 = *(const bf16x8*)(Kg + (size_t)(kn + r0) * 64 + o0);
            kreg1 = *(const bf16x8*)(Kg + (size_t)(kn + r1) * 64 + o1);
            vreg0 = *(const bf16x8*)(Vg + (size_t)r0 * 2048 + kn + o0);
            vreg1 = *(const bf16x8*)(Vg + (size_t)r1 * 2048 + kn + o1);
            rr[0][0] = *(const bf16x8*)(relW + (size_t)ktn * 1024);
            rr[0][1] = *(const bf16x8*)(relW + (size_t)ktn * 1024 + 8);
            rr[1][0] = *(const bf16x8*)(relW + 32768 + (size_t)ktn * 1024);
            rr[1][1] = *(const bf16x8*)(relW + 32768 + (size_t)ktn * 1024 + 8);
            __syncthreads();

            if (kt < mytiles) {
                // ---- scores: C init = rel' (done above), MFMA adds scaled QK^T ----
#pragma unroll
                for (int nt = 0; nt < 4; ++nt) {
                    bf16x8 kb0 = *(const bf16x8*)(Ks + (nt * 16 + l16) * 72 + quad * 8);
                    bf16x8 kb1 = *(const bf16x8*)(Ks + (nt * 16 + l16) * 72 + 32 + quad * 8);
#pragma unroll
                    for (int mt = 0; mt < 2; ++mt) {
                        s[mt][nt] = __builtin_amdgcn_mfma_f32_16x16x32_bf16(qa[mt][0], kb0, s[mt][nt], 0, 0, 0);
                        s[mt][nt] = __builtin_amdgcn_mfma_f32_16x16x32_bf16(qa[mt][1], kb1, s[mt][nt], 0, 0, 0);
                    }
                }
                // ---- causal mask (diagonal tile only) ----
                if (kt == mytiles - 1) {
#pragma unroll
                    for (int mt = 0; mt < 2; ++mt)
#pragma unroll
                        for (int nt = 0; nt < 4; ++nt)
#pragma unroll
                            for (int g = 0; g < 4; ++g) {
                                const int q = q0w + mt * 16 + quad * 4 + g;
                                const int k = k0 + nt * 16 + l16;
                                if (k > q) s[mt][nt][g] = -1e30f;
                            }
                }
                // ---- online softmax (exp2 domain) ----
#pragma unroll
                for (int mt = 0; mt < 2; ++mt) {
                    f32x4 t;
#pragma unroll
                    for (int g = 0; g < 4; ++g)
                        t[g] = fmaxf(fmaxf(s[mt][0][g], s[mt][1][g]), fmaxf(s[mt][2][g], s[mt][3][g]));
#pragma unroll
                    for (int off = 1; off < 16; off <<= 1)
#pragma unroll
                        for (int g = 0; g < 4; ++g)
                            t[g] = fmaxf(t[g], __shfl_xor(t[g], off, 64));
                    f32x4 mn, alpha;
#pragma unroll
                    for (int g = 0; g < 4; ++g) {
                        mn[g] = fmaxf(mrow[mt][g], t[g]);
                        alpha[g] = __builtin_amdgcn_exp2f(mrow[mt][g] - mn[g]);
                    }
                    mrow[mt] = mn;
#pragma unroll
                    for (int g = 0; g < 4; ++g) lrow[mt][g] *= alpha[g];
#pragma unroll
                    for (int dt = 0; dt < 4; ++dt)
#pragma unroll
                        for (int g = 0; g < 4; ++g) o[mt][dt][g] *= alpha[g];
#pragma unroll
                    for (int nt = 0; nt < 4; ++nt)
#pragma unroll
                        for (int g = 0; g < 4; ++g)
                            s[mt][nt][g] = __builtin_amdgcn_exp2f(s[mt][nt][g] - mn[g]);
                    f32x4 rs;
#pragma unroll
                    for (int g = 0; g < 4; ++g)
                        rs[g] = (s[mt][0][g] + s[mt][1][g]) + (s[mt][2][g] + s[mt][3][g]);
#pragma unroll
                    for (int off = 1; off < 16; off <<= 1)
#pragma unroll
                        for (int g = 0; g < 4; ++g)
                            rs[g] += __shfl_xor(rs[g], off, 64);
#pragma unroll
                    for (int g = 0; g < 4; ++g) lrow[mt][g] += rs[g];
                }
                // ---- P -> bf16 -> per-wave LDS ----
#pragma unroll
                for (int mt = 0; mt < 2; ++mt)
#pragma unroll
                    for (int nt = 0; nt < 4; ++nt)
#pragma unroll
                        for (int g = 0; g < 4; ++g)
                            Pl[(mt * 16 + quad * 4 + g) * 72 + nt * 16 + l16] = f2b(s[mt][nt][g]);
                // ---- PV ----
                bf16x8 pa[2][2];
#pragma unroll
                for (int mt = 0; mt < 2; ++mt)
#pragma unroll
                    for (int ks = 0; ks < 2; ++ks)
                        pa[mt][ks] = *(const bf16x8*)(Pl + (mt * 16 + l16) * 72 + ks * 32 + quad * 8);
#pragma unroll
                for (int dt = 0; dt < 4; ++dt) {
                    bf16x8 vb0 = *(const bf16x8*)(Vt + (dt * 16 + l16) * 72 + quad * 8);
                    bf16x8 vb1 = *(const bf16x8*)(Vt + (dt * 16 + l16) * 72 + 32 + quad * 8);
#pragma unroll
                    for (int mt = 0; mt < 2; ++mt) {
                        o[mt][dt] = __builtin_amdgcn_mfma_f32_16x16x32_bf16(pa[mt][0], vb0, o[mt][dt], 0, 0, 0);
                        o[mt][dt] = __builtin_amdgcn_mfma_f32_16x16x32_bf16(pa[mt][1], vb1, o[mt][dt], 0, 0, 0);
                    }
                }
            }
            __syncthreads();
        }

        // ---- epilogue: O/l -> per-wave LDS -> coalesced stores ----
#pragma unroll
        for (int mt = 0; mt < 2; ++mt) {
            f32x4 linv;
#pragma unroll
            for (int g = 0; g < 4; ++g) linv[g] = 1.0f / lrow[mt][g];
#pragma unroll
            for (int dt = 0; dt < 4; ++dt)
#pragma unroll
                for (int g = 0; g < 4; ++g)
                    Pl[(mt * 16 + quad * 4 + g) * 72 + dt * 16 + l16] = f2b(o[mt][dt][g] * linv[g]);
        }
#pragma unroll
        for (int pp = 0; pp < 4; ++pp) {
            const int c = lane + pp * 64;
            const int row = c >> 3, col = (c & 7) << 3;
            bf16x8 t = *(const bf16x8*)(Pl + row * 72 + col);
            *(bf16x8*)(Ob + ((size_t)b * SEQ + q0w + row) * HID + h * DH + col) = t;
        }
    }
}

// ---------------- Output projection: bf16 LDS-staged GEMM, out = O @ Wout^T + bout ----------------
__global__ __launch_bounds__(256) void out_proj_kernel(
    const u16* __restrict__ X, const u16* __restrict__ W,
    const float* __restrict__ bias, float* __restrict__ out)
{
    __shared__ __align__(16) u16 As[128 * 32];
    __shared__ __align__(16) u16 Bs[128 * 32];

    const int tid  = threadIdx.x;
    const int w    = tid >> 6;
    const int lane = tid & 63;
    const int l16  = lane & 15;
    const int quad = lane >> 4;

    const int bid = blockIdx.x;
    const int tm = bid >> 3, tn = bid & 7;
    const int m0 = tm << 7, n0 = tn << 7;

    const int crow = lane >> 2;
    const int cofs = (lane & 3) << 3;

    f32x4 acc[4][4];
    const f32x4 zero = {0.f, 0.f, 0.f, 0.f};
#pragma unroll
    for (int r = 0; r < 4; ++r)
#pragma unroll
        for (int c = 0; c < 4; ++c) acc[r][c] = zero;

    const int wr = (w >> 1) << 6;
    const int wc = (w & 1) << 6;

    for (int k0 = 0; k0 < 1024; k0 += 32) {
#pragma unroll
        for (int c = 0; c < 2; ++c) {
            const int ch  = w + c * 4;
            const int row = ch * 16 + crow;
            gload_lds16(X + (size_t)(m0 + row) * 1024 + k0 + cofs, As + ch * 512 + lane * 8);
            gload_lds16(W + (size_t)(n0 + row) * 1024 + k0 + cofs, Bs + ch * 512 + lane * 8);
        }
        __syncthreads();
        bf16x8 a[4], b[4];
#pragma unroll
        for (int r = 0; r < 4; ++r) a[r] = *(const bf16x8*)(As + (wr + r * 16 + l16) * 32 + quad * 8);
#pragma unroll
        for (int c = 0; c < 4; ++c) b[c] = *(const bf16x8*)(Bs + (wc + c * 16 + l16) * 32 + quad * 8);
#pragma unroll
        for (int r = 0; r < 4; ++r)
#pragma unroll
            for (int c = 0; c < 4; ++c)
                acc[r][c] = __builtin_amdgcn_mfma_f32_16x16x32_bf16(a[r], b[c], acc[r][c], 0, 0, 0);
        __syncthreads();
    }

#pragma unroll
    for (int c = 0; c < 4; ++c) {
        const int n = n0 + wc + c * 16 + l16;
        const float bn = bias[n];
#pragma unroll
        for (int r = 0; r < 4; ++r) {
#pragma unroll
            for (int g = 0; g < 4; ++g) {
                const int m = m0 + wr + r * 16 + quad * 4 + g;
                out[(size_t)m * 1024 + n] = acc[r][c][g] + bn;
            }
        }
    }
}

extern "C" void kernel_launch(void* const* d_in, const int* in_sizes, int n_in,
                              void* d_out, int out_size, void* d_ws, size_t ws_size,
                              hipStream_t stream)
{
    const float* q   = (const float*)d_in[0];
    const float* k   = (const float*)d_in[1];
    const float* v   = (const float*)d_in[2];
    const float* rel = (const float*)d_in[3];
    // d_in[4] = attn_mask: statically causal tril, not read
    const float* wq = (const float*)d_in[5];  const float* bq = (const float*)d_in[6];
    const float* wk = (const float*)d_in[7];  const float* bk = (const float*)d_in[8];
    const float* wv = (const float*)d_in[9];  const float* bv = (const float*)d_in[10];
    const float* wo = (const float*)d_in[11]; const float* bo = (const float*)d_in[12];

    u16* ws = (u16*)d_ws;                 // 96 MB used
    u16* Qw   = ws;
    u16* Kw   = ws + 8388608ULL;
    u16* Vw   = ws + 16777216ULL;
    u16* Ow   = ws + 25165824ULL;
    u16* relb = ws + 33554432ULL;

    // bf16 staging aliases (dead by the time their hosts are written):
    u16* Xqb = Ow;                         // overwritten by attn (after qkv)
    u16* Xkb = relb;                       // overwritten by rel_perm (after qkv)
    u16* Xvb = relb + 8388608ULL;
    u16* Wqb = (u16*)d_out;                // d_out as scratch; out_proj rewrites it
    u16* Wkb = Wqb + 1048576ULL;
    u16* Wvb = Wqb + 2097152ULL;
    u16* Wob = Qw;                         // Qw dead after attn

    // X, W -> bf16
    cvt_bf16_kernel<<<1024, 256, 0, stream>>>(q, Xqb, 1048576);
    cvt_bf16_kernel<<<1024, 256, 0, stream>>>(k, Xkb, 1048576);
    cvt_bf16_kernel<<<1024, 256, 0, stream>>>(v, Xvb, 1048576);
    cvt_bf16_kernel<<<512, 256, 0, stream>>>(wq, Wqb, 131072);
    cvt_bf16_kernel<<<512, 256, 0, stream>>>(wk, Wkb, 131072);
    cvt_bf16_kernel<<<512, 256, 0, stream>>>(wv, Wvb, 131072);

    qkv_proj_kernel<<<1536, 256, 0, stream>>>(Xqb, Xkb, Xvb, Wqb, Wkb, Wvb,
                                              bq, bk, bv, Qw, Kw, Vw);
    rel_perm_kernel<<<4096, 256, 0, stream>>>(rel, relb);    // overwrites Xkb/Xvb (dead)
    attn_kernel<<<512, 256, 0, stream>>>(Qw, Kw, Vw, relb, Ow);   // overwrites Xqb (dead)
    cvt_bf16_kernel<<<512, 256, 0, stream>>>(wo, Wob, 131072);    // into dead Qw region
    out_proj_kernel<<<512, 256, 0, stream>>>(Ow, Wob, bo, (float*)d_out);
}